// Round 1
// baseline (230.358 us; speedup 1.0000x reference)
//
#include <hip/hip_runtime.h>

// Problem constants (match reference setup_inputs)
#define NB 8
#define NM 64
#define NA 49104
#define NC 80
#define EPSF 1e-4f

struct Ws {
    float neg[NB];      // sum of negative-branch focal terms over all A*C
    float corr[NB];     // positive-anchor correction terms
    float regs[NB];     // smooth-L1 sum over positive anchors
    unsigned int npos[NB];
};

__device__ __forceinline__ float waveReduceSumF(float v) {
    #pragma unroll
    for (int off = 32; off > 0; off >>= 1) v += __shfl_down(v, off, 64);
    return v;
}
__device__ __forceinline__ unsigned int waveReduceSumU(unsigned int v) {
    #pragma unroll
    for (int off = 32; off > 0; off >>= 1) v += __shfl_down(v, off, 64);
    return v;
}

// Kernel A: neg_sum[j] = sum over all anchors/classes of 0.75 * p^2 * (-log(1-p))
__global__ void neg_sum_kernel(const float4* __restrict__ cls, Ws* __restrict__ ws) {
    const int j = blockIdx.y;
    const int per_img4 = NA * NC / 4;  // 982080
    const float4* base = cls + (size_t)j * per_img4;
    float s = 0.0f;
    for (int i = blockIdx.x * blockDim.x + threadIdx.x; i < per_img4;
         i += gridDim.x * blockDim.x) {
        float4 v = base[i];
        float pv[4] = {v.x, v.y, v.z, v.w};
        #pragma unroll
        for (int k = 0; k < 4; ++k) {
            float p = fminf(fmaxf(pv[k], EPSF), 1.0f - EPSF);
            s += p * p * (-logf(1.0f - p));
        }
    }
    s *= 0.75f;
    s = waveReduceSumF(s);
    if ((threadIdx.x & 63) == 0) atomicAdd(&ws->neg[j], s);
}

// Kernel B: per-anchor IoU argmax over 64 boxes, pos flag, focal correction,
// smooth-L1 regression.
__global__ void anchor_kernel(const float* __restrict__ boxes,
                              const int* __restrict__ labels,
                              const float* __restrict__ anchors,
                              const float* __restrict__ cls,
                              const float4* __restrict__ reg,
                              Ws* __restrict__ ws) {
    const int j = blockIdx.y;
    __shared__ float bx1[NM], by1[NM], bx2[NM], by2[NM], barea[NM];
    __shared__ int blab[NM];
    if (threadIdx.x < NM) {
        int m = threadIdx.x;
        const float* b = boxes + ((size_t)j * NM + m) * 4;
        float x1 = b[0], y1 = b[1], x2 = b[2], y2 = b[3];
        bx1[m] = x1; by1[m] = y1; bx2[m] = x2; by2[m] = y2;
        barea[m] = (x2 - x1) * (y2 - y1);
        blab[m] = labels[j * NM + m];
    }
    __syncthreads();

    const int a = blockIdx.x * blockDim.x + threadIdx.x;
    float corr = 0.0f, regl = 0.0f;
    unsigned int np = 0;
    if (a < NA) {
        float4 an = ((const float4*)anchors)[a];  // (y1,x1,y2,x2)
        const float ay1 = an.x, ax1 = an.y, ay2 = an.z, ax2 = an.w;
        const float aarea = (ay2 - ay1) * (ax2 - ax1);
        float best = -2.0f;
        int bi = 0;
        #pragma unroll 8
        for (int m = 0; m < NM; ++m) {
            float iw = fminf(ax2, bx2[m]) - fmaxf(ax1, bx1[m]);
            float ih = fminf(ay2, by2[m]) - fmaxf(ay1, by1[m]);
            iw = fmaxf(iw, 0.0f);
            ih = fmaxf(ih, 0.0f);
            float inter = iw * ih;
            float ua = fmaxf(aarea + barea[m] - inter, 1e-8f);
            float iou = inter / ua;
            if (blab[m] == 0) iou = -1.0f;   // mask padded GT
            if (iou > best) { best = iou; bi = m; }  // first-max (JAX argmax)
        }
        const bool big = barea[bi] > 100.0f;
        const bool pos = big ? (best >= 0.5f) : (best >= 0.15f);
        if (pos) {
            np = 1;
            const int al = blab[bi] - 1;  // guaranteed >= 0 when pos
            float p = cls[((size_t)j * NA + a) * NC + al];
            p = fminf(fmaxf(p, EPSF), 1.0f - EPSF);
            const float om = 1.0f - p;
            // positive term minus the negative term already counted in neg_sum
            corr = 0.25f * om * om * (-logf(p)) - 0.75f * p * p * (-logf(om));

            // regression
            const float aw = ax2 - ax1, ah = ay2 - ay1;
            const float acx = ax1 + 0.5f * aw, acy = ay1 + 0.5f * ah;
            float gw = bx2[bi] - bx1[bi];
            float gh = by2[bi] - by1[bi];
            const float gcx = bx1[bi] + 0.5f * gw;
            const float gcy = by1[bi] + 0.5f * gh;
            gw = fmaxf(gw, 1.0f);
            gh = fmaxf(gh, 1.0f);
            float4 r = reg[(size_t)j * NA + a];
            const float t0 = (gcy - acy) / ah;
            const float t1 = (gcx - acx) / aw;
            const float t2 = logf(gh / ah);
            const float t3 = logf(gw / aw);
            const float d0 = fabsf(t0 - r.x);
            const float d1 = fabsf(t1 - r.y);
            const float d2 = fabsf(t2 - r.z);
            const float d3 = fabsf(t3 - r.w);
            const float ninth = 1.0f / 9.0f;
            const float c = 0.5f / 9.0f;
            regl  = (d0 <= ninth) ? 4.5f * d0 * d0 : d0 - c;
            regl += (d1 <= ninth) ? 4.5f * d1 * d1 : d1 - c;
            regl += (d2 <= ninth) ? 4.5f * d2 * d2 : d2 - c;
            regl += (d3 <= ninth) ? 4.5f * d3 * d3 : d3 - c;
        }
    }
    corr = waveReduceSumF(corr);
    regl = waveReduceSumF(regl);
    np = waveReduceSumU(np);
    if ((threadIdx.x & 63) == 0) {
        if (corr != 0.0f) atomicAdd(&ws->corr[j], corr);
        if (regl != 0.0f) atomicAdd(&ws->regs[j], regl);
        if (np) atomicAdd(&ws->npos[j], np);
    }
}

// Kernel C: finalize the 8 per-image sums into 2 output scalars.
__global__ void finalize_kernel(const Ws* __restrict__ ws, float* __restrict__ out) {
    if (threadIdx.x == 0 && blockIdx.x == 0) {
        float cs = 0.0f, rs = 0.0f;
        #pragma unroll
        for (int j = 0; j < NB; ++j) {
            float np = (float)ws->npos[j];
            float d = fmaxf(np, 1.0f);
            cs += (ws->neg[j] + ws->corr[j]) / d;
            rs += (np > 0.0f) ? ws->regs[j] / (4.0f * d) : 0.0f;
        }
        out[0] = cs / (float)NB;
        out[1] = (rs / (float)NB) * 50.0f;
    }
}

extern "C" void kernel_launch(void* const* d_in, const int* in_sizes, int n_in,
                              void* d_out, int out_size, void* d_ws, size_t ws_size,
                              hipStream_t stream) {
    const float* boxes   = (const float*)d_in[0];
    const int*   labels  = (const int*)d_in[1];
    const float* anchors = (const float*)d_in[2];
    const float* cls     = (const float*)d_in[3];
    const float* reg     = (const float*)d_in[4];
    float* out = (float*)d_out;
    Ws* ws = (Ws*)d_ws;

    hipMemsetAsync(d_ws, 0, sizeof(Ws), stream);

    dim3 gA(120, NB);
    neg_sum_kernel<<<gA, 256, 0, stream>>>((const float4*)cls, ws);

    dim3 gB((NA + 255) / 256, NB);
    anchor_kernel<<<gB, 256, 0, stream>>>(boxes, labels, anchors, cls,
                                          (const float4*)reg, ws);

    finalize_kernel<<<1, 64, 0, stream>>>(ws, out);
}

// Round 2
// 181.486 us; speedup vs baseline: 1.2693x; 1.2693x over previous
//
#include <hip/hip_runtime.h>

// Problem constants (match reference setup_inputs)
#define NB 8
#define NM 64
#define NA 49104
#define NC 80
#define EPSF 1e-4f
#define APT 4   // anchors per thread in anchor_kernel

struct Ws {
    float neg[NB];      // sum of negative-branch focal terms over all A*C
    float corr[NB];     // positive-anchor correction terms
    float regs[NB];     // smooth-L1 sum over positive anchors
    unsigned int npos[NB];
};

__device__ __forceinline__ float waveReduceSumF(float v) {
    #pragma unroll
    for (int off = 32; off > 0; off >>= 1) v += __shfl_down(v, off, 64);
    return v;
}
__device__ __forceinline__ unsigned int waveReduceSumU(unsigned int v) {
    #pragma unroll
    for (int off = 32; off > 0; off >>= 1) v += __shfl_down(v, off, 64);
    return v;
}

// Kernel A: neg[j] = sum over all A*C of 0.75 * p^2 * (-log(1-p))
__global__ void neg_sum_kernel(const float4* __restrict__ cls, Ws* __restrict__ ws) {
    const int j = blockIdx.y;
    const int per4 = NA * NC / 4;  // 982080
    const float4* base = cls + (size_t)j * per4;
    float s0 = 0.0f, s1 = 0.0f;
    const int stride = gridDim.x * blockDim.x;
    for (int i = blockIdx.x * blockDim.x + threadIdx.x; i < per4; i += stride) {
        float4 v = base[i];
        float p0 = fminf(fmaxf(v.x, EPSF), 1.0f - EPSF);
        float p1 = fminf(fmaxf(v.y, EPSF), 1.0f - EPSF);
        float p2 = fminf(fmaxf(v.z, EPSF), 1.0f - EPSF);
        float p3 = fminf(fmaxf(v.w, EPSF), 1.0f - EPSF);
        s0 += p0 * p0 * (-__logf(1.0f - p0));
        s1 += p1 * p1 * (-__logf(1.0f - p1));
        s0 += p2 * p2 * (-__logf(1.0f - p2));
        s1 += p3 * p3 * (-__logf(1.0f - p3));
    }
    float s = 0.75f * (s0 + s1);
    s = waveReduceSumF(s);
    if ((threadIdx.x & 63) == 0) atomicAdd(&ws->neg[j], s);
}

// Kernel B: per-anchor IoU argmax over 64 boxes (division-free), pos flag,
// focal correction, smooth-L1 regression. APT anchors per thread for ILP.
__global__ void anchor_kernel(const float* __restrict__ boxes,
                              const int* __restrict__ labels,
                              const float4* __restrict__ anchors4,
                              const float* __restrict__ cls,
                              const float4* __restrict__ reg,
                              Ws* __restrict__ ws) {
    const int j = blockIdx.y;
    __shared__ float4 sboxA[NM];   // x1,y1,x2,y2
    __shared__ float2 sboxB[NM];   // area, label(as float)
    if (threadIdx.x < NM) {
        const int m = threadIdx.x;
        float4 b = ((const float4*)boxes)[j * NM + m];
        sboxA[m] = b;
        sboxB[m] = make_float2((b.z - b.x) * (b.w - b.y), (float)labels[j * NM + m]);
    }
    __syncthreads();

    const int aBase = blockIdx.x * blockDim.x * APT + threadIdx.x;

    float ax1[APT], ay1[APT], ax2[APT], ay2[APT], aare[APT];
    float besti[APT], bestu[APT];
    int bi[APT];
    #pragma unroll
    for (int k = 0; k < APT; ++k) {
        int a = aBase + k * 256;
        int ai = a < NA ? a : NA - 1;
        float4 an = anchors4[ai];          // (y1,x1,y2,x2)
        ay1[k] = an.x; ax1[k] = an.y; ay2[k] = an.z; ax2[k] = an.w;
        aare[k] = (an.z - an.x) * (an.w - an.y);
        besti[k] = -2.0f; bestu[k] = 1.0f; bi[k] = 0;
    }

    #pragma unroll 4
    for (int m = 0; m < NM; ++m) {
        float4 b = sboxA[m];     // x1,y1,x2,y2
        float2 e = sboxB[m];     // area, labelf
        #pragma unroll
        for (int k = 0; k < APT; ++k) {
            float iw = fminf(ax2[k], b.z) - fmaxf(ax1[k], b.x);
            float ih = fminf(ay2[k], b.w) - fmaxf(ay1[k], b.y);
            iw = fmaxf(iw, 0.0f);
            ih = fmaxf(ih, 0.0f);
            float inter = iw * ih;
            float ua = fmaxf(aare[k] + e.x - inter, 1e-8f);
            // masked GT (label==0): iou = -1 exactly  ->  numer = -ua
            float numer = (e.y != 0.0f) ? inter : -ua;
            // iou_m > best  <=>  numer*bestu > besti*ua   (ua,bestu > 0)
            bool upd = numer * bestu[k] > besti[k] * ua;
            besti[k] = upd ? numer : besti[k];
            bestu[k] = upd ? ua : bestu[k];
            bi[k]    = upd ? m : bi[k];
        }
    }

    float corr = 0.0f, regl = 0.0f;
    unsigned int np = 0;
    #pragma unroll
    for (int k = 0; k < APT; ++k) {
        int a = aBase + k * 256;
        if (a >= NA) continue;
        float4 bb = sboxA[bi[k]];
        float2 ee = sboxB[bi[k]];
        const bool big = ee.x > 100.0f;
        const float thr = big ? 0.5f : 0.15f;
        const bool pos = besti[k] >= thr * bestu[k];
        if (pos) {
            np += 1;
            const int al = (int)ee.y - 1;   // label>=1 guaranteed when pos
            float p = cls[((size_t)j * NA + a) * NC + al];
            p = fminf(fmaxf(p, EPSF), 1.0f - EPSF);
            const float om = 1.0f - p;
            corr += 0.25f * om * om * (-__logf(p)) - 0.75f * p * p * (-__logf(om));

            const float aw = ax2[k] - ax1[k], ah = ay2[k] - ay1[k];
            const float acx = ax1[k] + 0.5f * aw, acy = ay1[k] + 0.5f * ah;
            float gw = bb.z - bb.x;
            float gh = bb.w - bb.y;
            const float gcx = bb.x + 0.5f * gw;
            const float gcy = bb.y + 0.5f * gh;
            gw = fmaxf(gw, 1.0f);
            gh = fmaxf(gh, 1.0f);
            float4 r = reg[(size_t)j * NA + a];
            const float t0 = (gcy - acy) / ah;
            const float t1 = (gcx - acx) / aw;
            const float t2 = __logf(gh / ah);
            const float t3 = __logf(gw / aw);
            const float d0 = fabsf(t0 - r.x);
            const float d1 = fabsf(t1 - r.y);
            const float d2 = fabsf(t2 - r.z);
            const float d3 = fabsf(t3 - r.w);
            const float ninth = 1.0f / 9.0f;
            const float c = 0.5f / 9.0f;
            regl += (d0 <= ninth) ? 4.5f * d0 * d0 : d0 - c;
            regl += (d1 <= ninth) ? 4.5f * d1 * d1 : d1 - c;
            regl += (d2 <= ninth) ? 4.5f * d2 * d2 : d2 - c;
            regl += (d3 <= ninth) ? 4.5f * d3 * d3 : d3 - c;
        }
    }
    corr = waveReduceSumF(corr);
    regl = waveReduceSumF(regl);
    np = waveReduceSumU(np);
    if ((threadIdx.x & 63) == 0) {
        if (corr != 0.0f) atomicAdd(&ws->corr[j], corr);
        if (regl != 0.0f) atomicAdd(&ws->regs[j], regl);
        if (np) atomicAdd(&ws->npos[j], np);
    }
}

// Kernel C: finalize the 8 per-image sums into 2 output scalars.
__global__ void finalize_kernel(const Ws* __restrict__ ws, float* __restrict__ out) {
    if (threadIdx.x == 0 && blockIdx.x == 0) {
        float cs = 0.0f, rs = 0.0f;
        #pragma unroll
        for (int j = 0; j < NB; ++j) {
            float np = (float)ws->npos[j];
            float d = fmaxf(np, 1.0f);
            cs += (ws->neg[j] + ws->corr[j]) / d;
            rs += (np > 0.0f) ? ws->regs[j] / (4.0f * d) : 0.0f;
        }
        out[0] = cs / (float)NB;
        out[1] = (rs / (float)NB) * 50.0f;
    }
}

extern "C" void kernel_launch(void* const* d_in, const int* in_sizes, int n_in,
                              void* d_out, int out_size, void* d_ws, size_t ws_size,
                              hipStream_t stream) {
    const float* boxes   = (const float*)d_in[0];
    const int*   labels  = (const int*)d_in[1];
    const float* anchors = (const float*)d_in[2];
    const float* cls     = (const float*)d_in[3];
    const float* reg     = (const float*)d_in[4];
    float* out = (float*)d_out;
    Ws* ws = (Ws*)d_ws;

    hipMemsetAsync(d_ws, 0, sizeof(Ws), stream);

    dim3 gA(256, NB);   // 2048 blocks -> 8 blocks/CU, saturate HBM
    neg_sum_kernel<<<gA, 256, 0, stream>>>((const float4*)cls, ws);

    dim3 gB((NA + 256 * APT - 1) / (256 * APT), NB);  // 48 x 8
    anchor_kernel<<<gB, 256, 0, stream>>>(boxes, labels, (const float4*)anchors,
                                          cls, (const float4*)reg, ws);

    finalize_kernel<<<1, 64, 0, stream>>>(ws, out);
}

// Round 3
// 52.717 us; speedup vs baseline: 4.3697x; 3.4426x over previous
//
#include <hip/hip_runtime.h>

// Problem constants (match reference setup_inputs)
#define NB 8
#define NM 64
#define NA 49104
#define NC 80
#define EPSF 1e-4f
#define APT 4      // anchors per thread (anchor role)
#define NEGB 256   // neg-role blocks per image
#define ANCB 48    // anchor-role blocks per image (48*256*4 = 49152 >= 49104)

// Per-block partials. Every slot is written unconditionally each launch,
// so no zero-init / memset is required (d_ws poison is overwritten).
struct Ws {
    float negp[NB][NEGB];
    float corrp[NB][ANCB];
    float regp[NB][ANCB];
    float npp[NB][ANCB];
};

__device__ __forceinline__ float waveReduceSumF(float v) {
    #pragma unroll
    for (int off = 32; off > 0; off >>= 1) v += __shfl_down(v, off, 64);
    return v;
}

__global__ void main_kernel(const float* __restrict__ boxes,
                            const int* __restrict__ labels,
                            const float4* __restrict__ anchors4,
                            const float* __restrict__ cls,
                            const float4* __restrict__ reg,
                            Ws* __restrict__ ws) {
    const int j = blockIdx.y;
    __shared__ float4 sboxA[NM];     // x1,y1,x2,y2
    __shared__ float2 sboxB[NM];     // area, label(as float)
    __shared__ float sred[3][4];

    if (blockIdx.x < NEGB) {
        // ---- neg role: sum 0.75 * p^2 * (-log(1-p)) over this image's slice ----
        const int per4 = NA * NC / 4;  // 982080
        const float4* base = (const float4*)cls + (size_t)j * per4;
        float s0 = 0.0f, s1 = 0.0f;
        const int stride = NEGB * 256;
        for (int i = blockIdx.x * 256 + threadIdx.x; i < per4; i += stride) {
            float4 v = base[i];
            float p0 = fminf(fmaxf(v.x, EPSF), 1.0f - EPSF);
            float p1 = fminf(fmaxf(v.y, EPSF), 1.0f - EPSF);
            float p2 = fminf(fmaxf(v.z, EPSF), 1.0f - EPSF);
            float p3 = fminf(fmaxf(v.w, EPSF), 1.0f - EPSF);
            s0 += p0 * p0 * (-__logf(1.0f - p0));
            s1 += p1 * p1 * (-__logf(1.0f - p1));
            s0 += p2 * p2 * (-__logf(1.0f - p2));
            s1 += p3 * p3 * (-__logf(1.0f - p3));
        }
        float s = 0.75f * (s0 + s1);
        s = waveReduceSumF(s);
        const int wid = threadIdx.x >> 6;
        if ((threadIdx.x & 63) == 0) sred[0][wid] = s;
        __syncthreads();
        if (threadIdx.x == 0)
            ws->negp[j][blockIdx.x] = sred[0][0] + sred[0][1] + sred[0][2] + sred[0][3];
    } else {
        // ---- anchor role: IoU argmax (division-free), focal correction, smooth-L1 ----
        const int bx = blockIdx.x - NEGB;
        if (threadIdx.x < NM) {
            const int m = threadIdx.x;
            float4 b = ((const float4*)boxes)[j * NM + m];
            sboxA[m] = b;
            sboxB[m] = make_float2((b.z - b.x) * (b.w - b.y),
                                   (float)labels[j * NM + m]);
        }
        __syncthreads();

        const int aBase = bx * 256 * APT + threadIdx.x;
        float ax1[APT], ay1[APT], ax2[APT], ay2[APT], aare[APT];
        float besti[APT], bestu[APT];
        int bi[APT];
        #pragma unroll
        for (int k = 0; k < APT; ++k) {
            int a = aBase + k * 256;
            int ai = a < NA ? a : NA - 1;
            float4 an = anchors4[ai];      // (y1,x1,y2,x2)
            ay1[k] = an.x; ax1[k] = an.y; ay2[k] = an.z; ax2[k] = an.w;
            aare[k] = (an.z - an.x) * (an.w - an.y);
            besti[k] = -2.0f; bestu[k] = 1.0f; bi[k] = 0;
        }

        #pragma unroll 4
        for (int m = 0; m < NM; ++m) {
            float4 b = sboxA[m];
            float2 e = sboxB[m];
            #pragma unroll
            for (int k = 0; k < APT; ++k) {
                float iw = fminf(ax2[k], b.z) - fmaxf(ax1[k], b.x);
                float ih = fminf(ay2[k], b.w) - fmaxf(ay1[k], b.y);
                iw = fmaxf(iw, 0.0f);
                ih = fmaxf(ih, 0.0f);
                float inter = iw * ih;
                float ua = fmaxf(aare[k] + e.x - inter, 1e-8f);
                // masked GT (label==0): iou = -1 exactly -> numer = -ua
                float numer = (e.y != 0.0f) ? inter : -ua;
                // iou_m > best  <=>  numer*bestu > besti*ua  (ua,bestu > 0)
                bool upd = numer * bestu[k] > besti[k] * ua;
                besti[k] = upd ? numer : besti[k];
                bestu[k] = upd ? ua : bestu[k];
                bi[k]    = upd ? m : bi[k];
            }
        }

        float corr = 0.0f, regl = 0.0f, npf = 0.0f;
        #pragma unroll
        for (int k = 0; k < APT; ++k) {
            int a = aBase + k * 256;
            if (a >= NA) continue;
            float4 bb = sboxA[bi[k]];
            float2 ee = sboxB[bi[k]];
            const bool big = ee.x > 100.0f;
            const float thr = big ? 0.5f : 0.15f;
            const bool pos = besti[k] >= thr * bestu[k];
            if (pos) {
                npf += 1.0f;
                const int al = (int)ee.y - 1;  // label>=1 guaranteed when pos
                float p = cls[((size_t)j * NA + a) * NC + al];
                p = fminf(fmaxf(p, EPSF), 1.0f - EPSF);
                const float om = 1.0f - p;
                corr += 0.25f * om * om * (-__logf(p)) - 0.75f * p * p * (-__logf(om));

                const float aw = ax2[k] - ax1[k], ah = ay2[k] - ay1[k];
                const float acx = ax1[k] + 0.5f * aw, acy = ay1[k] + 0.5f * ah;
                float gw = bb.z - bb.x;
                float gh = bb.w - bb.y;
                const float gcx = bb.x + 0.5f * gw;
                const float gcy = bb.y + 0.5f * gh;
                gw = fmaxf(gw, 1.0f);
                gh = fmaxf(gh, 1.0f);
                float4 r = reg[(size_t)j * NA + a];
                const float t0 = (gcy - acy) / ah;
                const float t1 = (gcx - acx) / aw;
                const float t2 = __logf(gh / ah);
                const float t3 = __logf(gw / aw);
                const float d0 = fabsf(t0 - r.x);
                const float d1 = fabsf(t1 - r.y);
                const float d2 = fabsf(t2 - r.z);
                const float d3 = fabsf(t3 - r.w);
                const float ninth = 1.0f / 9.0f;
                const float c = 0.5f / 9.0f;
                regl += (d0 <= ninth) ? 4.5f * d0 * d0 : d0 - c;
                regl += (d1 <= ninth) ? 4.5f * d1 * d1 : d1 - c;
                regl += (d2 <= ninth) ? 4.5f * d2 * d2 : d2 - c;
                regl += (d3 <= ninth) ? 4.5f * d3 * d3 : d3 - c;
            }
        }
        corr = waveReduceSumF(corr);
        regl = waveReduceSumF(regl);
        npf  = waveReduceSumF(npf);
        const int wid = threadIdx.x >> 6;
        if ((threadIdx.x & 63) == 0) {
            sred[0][wid] = corr; sred[1][wid] = regl; sred[2][wid] = npf;
        }
        __syncthreads();
        if (threadIdx.x == 0) {
            ws->corrp[j][bx] = sred[0][0] + sred[0][1] + sred[0][2] + sred[0][3];
            ws->regp[j][bx]  = sred[1][0] + sred[1][1] + sred[1][2] + sred[1][3];
            ws->npp[j][bx]   = sred[2][0] + sred[2][1] + sred[2][2] + sred[2][3];
        }
    }
}

// Finalize: 8 waves, wave j reduces image j's partials; thread 0 emits output.
__global__ void finalize_kernel(const Ws* __restrict__ ws, float* __restrict__ out) {
    __shared__ float scls[NB], sreg[NB];
    const int w = threadIdx.x >> 6;     // image
    const int lane = threadIdx.x & 63;
    float ns = 0.0f;
    #pragma unroll
    for (int i = lane; i < NEGB; i += 64) ns += ws->negp[w][i];
    float cs = 0.0f, rs = 0.0f, np = 0.0f;
    if (lane < ANCB) {
        cs = ws->corrp[w][lane];
        rs = ws->regp[w][lane];
        np = ws->npp[w][lane];
    }
    ns = waveReduceSumF(ns);
    cs = waveReduceSumF(cs);
    rs = waveReduceSumF(rs);
    np = waveReduceSumF(np);
    if (lane == 0) {
        float d = fmaxf(np, 1.0f);
        scls[w] = (ns + cs) / d;
        sreg[w] = (np > 0.0f) ? rs / (4.0f * d) : 0.0f;
    }
    __syncthreads();
    if (threadIdx.x == 0) {
        float a = 0.0f, b = 0.0f;
        #pragma unroll
        for (int j = 0; j < NB; ++j) { a += scls[j]; b += sreg[j]; }
        out[0] = a / (float)NB;
        out[1] = (b / (float)NB) * 50.0f;
    }
}

extern "C" void kernel_launch(void* const* d_in, const int* in_sizes, int n_in,
                              void* d_out, int out_size, void* d_ws, size_t ws_size,
                              hipStream_t stream) {
    const float* boxes   = (const float*)d_in[0];
    const int*   labels  = (const int*)d_in[1];
    const float* anchors = (const float*)d_in[2];
    const float* cls     = (const float*)d_in[3];
    const float* reg     = (const float*)d_in[4];
    float* out = (float*)d_out;
    Ws* ws = (Ws*)d_ws;

    dim3 g(NEGB + ANCB, NB);
    main_kernel<<<g, 256, 0, stream>>>(boxes, labels, (const float4*)anchors,
                                       cls, (const float4*)reg, ws);
    finalize_kernel<<<1, 512, 0, stream>>>(ws, out);
}